// Round 10
// baseline (343.518 us; speedup 1.0000x reference)
//
#include <hip/hip_runtime.h>
#include <stdint.h>

// Shapes (fixed by the reference)
#define B_  4096
#define V_  5
#define D_  512
#define NN_ (B_ * V_)            // 20480 text rows
#define NBLK_ 5120               // gemm grid 32 x 160

// p = exp((dot - 1)/T) = exp2(dot*C - C), C = log2(e)/T
#define C_EXP 20.609929155556620f   // 1.4426950408889634 / 0.07
#define M_SHIFT (1.0f / 0.07f)

typedef _Float16 half8   __attribute__((ext_vector_type(8)));
typedef float    floatx4 __attribute__((ext_vector_type(4)));

// async global->LDS DMA, 16B per lane; LDS dest = wave-uniform base + lane*16
__device__ __forceinline__ void load_lds16(const _Float16* g, _Float16* l) {
  __builtin_amdgcn_global_load_lds(
      (const __attribute__((address_space(1))) unsigned int*)g,
      (__attribute__((address_space(3))) unsigned int*)l,
      16, 0, 0);
}

__device__ __forceinline__ float agent_load(const float* p) {
  return __hip_atomic_load(p, __ATOMIC_RELAXED, __HIP_MEMORY_SCOPE_AGENT);
}

// ---------------------------------------------------------------------------
// Kernel 1: PURE streaming fp32->f16 convert, 8 floats/thread/iter (16B
// stores — r9 used 8B stores), + zero accumulators and the done-counter.
// 2048 blocks x 256 threads x 3 iters x 8 floats = 12,582,912 exact.
// ---------------------------------------------------------------------------
__global__ void cvt_kernel(const float* __restrict__ img, const float* __restrict__ txt,
                           _Float16* __restrict__ outH, float* __restrict__ acc,
                           unsigned int* __restrict__ cnt) {
  const int tid0 = blockIdx.x * 256 + threadIdx.x;   // 0..524287
  if (tid0 < B_ + NN_) acc[tid0] = 0.0f;             // zero row/col sums
  if (tid0 == 0) *cnt = 0u;                          // zero done-counter
#pragma unroll
  for (int it = 0; it < 3; ++it) {
    const int i8 = tid0 + it * (2048 * 256);         // index in 8-float groups
    float4 a, b;
    if (i8 < (B_ * D_) / 8) {                        // img: first 262144 groups
      a = ((const float4*)img)[2 * i8];
      b = ((const float4*)img)[2 * i8 + 1];
    } else {
      const int j = i8 - (B_ * D_) / 8;
      a = ((const float4*)txt)[2 * j];
      b = ((const float4*)txt)[2 * j + 1];
    }
    union { _Float16 h[8]; float4 f4; } u;
    u.h[0] = (_Float16)a.x; u.h[1] = (_Float16)a.y;
    u.h[2] = (_Float16)a.z; u.h[3] = (_Float16)a.w;
    u.h[4] = (_Float16)b.x; u.h[5] = (_Float16)b.y;
    u.h[6] = (_Float16)b.z; u.h[7] = (_Float16)b.w;
    ((float4*)outH)[i8] = u.f4;
  }
}

// ---------------------------------------------------------------------------
// Kernel 2: fused GEMM + exp + row/col sums + positives + LAST-BLOCK FINISH.
// Superstep pipeline (r8/r9: one vmcnt-bearing drain per 2 kt), 128x128 tile,
// BK=32, 4 waves 2x2, XOR bank swizzle (0 conflicts). The final arriving
// block (device-scope counter) performs the loss reduction — removes the
// separate finish dispatch (r9: residue is dispatch/gap-dominated).
// ---------------------------------------------------------------------------
__global__ __launch_bounds__(256, 3)
void gemm_kernel(const _Float16* __restrict__ Ah, const _Float16* __restrict__ Bh,
                 float* __restrict__ row_sum, float* __restrict__ col_sum,
                 float* __restrict__ posPart, unsigned int* __restrict__ cnt,
                 float* __restrict__ out) {
  __shared__ __align__(16) _Float16 As[2][128 * 32];   // 16 KB
  __shared__ __align__(16) _Float16 Bs[2][128 * 32];   // 16 KB
  const int tid  = threadIdx.x;
  const int lane = tid & 63;
  const int w    = tid >> 6;                 // wave 0..3
  const int wm   = w >> 1, wn = w & 1;       // 2x2 wave grid
  const int m0   = blockIdx.x * 128;
  const int n0   = blockIdx.y * 128;

  floatx4 acc[4][4] = {};

  // --- staging (swizzled): lane L -> LDS row L>>2, chunk L&3; global chunk
  // fetched is (L&3)^((L>>3)&3), i.e. LDS(r,c) = global chunk c^((r>>1)&3).
  const int sc = ((lane & 3) ^ ((lane >> 3) & 3)) * 8;     // halves
  const _Float16* gA = Ah + (size_t)(m0 + w * 32 + (lane >> 2)) * D_ + sc;
  const _Float16* gB = Bh + (size_t)(n0 + w * 32 + (lane >> 2)) * D_ + sc;
  const int lofs = (w * 32) * 32;            // wave-uniform LDS offset

  // --- fragment addressing (matching un-swizzle) ---
  const int fr = lane & 15;                  // frag m/n index (lane&15)
  const int fj = ((lane >> 4) ^ ((fr >> 1) & 3)) * 8;      // swizzled k-chunk

  // prologue: stage kt0 -> buf0, kt1 -> buf1
  load_lds16(gA,           &As[0][lofs]);
  load_lds16(gA + 16 * D_, &As[0][lofs + 16 * 32]);
  load_lds16(gB,           &Bs[0][lofs]);
  load_lds16(gB + 16 * D_, &Bs[0][lofs + 16 * 32]);
  load_lds16(gA + 32,           &As[1][lofs]);
  load_lds16(gA + 32 + 16 * D_, &As[1][lofs + 16 * 32]);
  load_lds16(gB + 32,           &Bs[1][lofs]);
  load_lds16(gB + 32 + 16 * D_, &Bs[1][lofs + 16 * 32]);

  for (int ss = 0; ss < 8; ++ss) {           // 8 supersteps x 2 kt = K/32
    __syncthreads();   // barrier A: drains DMAs issued a full superstep ago

    half8 af[2][4], bf[2][4];
#pragma unroll
    for (int p = 0; p < 2; ++p)
#pragma unroll
      for (int f = 0; f < 4; ++f) {
        af[p][f] = *(const half8*)(&As[p][(wm * 64 + f * 16 + fr) * 32 + fj]);
        bf[p][f] = *(const half8*)(&Bs[p][(wn * 64 + f * 16 + fr) * 32 + fj]);
      }

    __syncthreads();   // barrier B: cheap (vmcnt already 0; lgkm drain needed anyway)

    if (ss < 7) {      // stage superstep ss+1 (overlaps the MFMAs below)
      const int kg = (2 * ss + 2) * 32;
      load_lds16(gA + kg,                &As[0][lofs]);
      load_lds16(gA + kg + 16 * D_,      &As[0][lofs + 16 * 32]);
      load_lds16(gB + kg,                &Bs[0][lofs]);
      load_lds16(gB + kg + 16 * D_,      &Bs[0][lofs + 16 * 32]);
      load_lds16(gA + kg + 32,           &As[1][lofs]);
      load_lds16(gA + kg + 32 + 16 * D_, &As[1][lofs + 16 * 32]);
      load_lds16(gB + kg + 32,           &Bs[1][lofs]);
      load_lds16(gB + kg + 32 + 16 * D_, &Bs[1][lofs + 16 * 32]);
    }

#pragma unroll
    for (int p = 0; p < 2; ++p)
#pragma unroll
      for (int mf = 0; mf < 4; ++mf)
#pragma unroll
        for (int nf = 0; nf < 4; ++nf)
          acc[mf][nf] = __builtin_amdgcn_mfma_f32_16x16x32_f16(af[p][mf], bf[p][nf], acc[mf][nf], 0, 0, 0);
  }

  // --- positive extraction from RAW acc (pre-exp): row == col/5 ---
  {
    float ps = 0.0f;
    const int iLo = n0 / 5, iHi = (n0 + 127) / 5;
    if (iHi >= m0 && iLo < m0 + 128) {       // block-uniform skip (~4/5 skip)
      const int rbase = m0 + wm * 64 + ((lane >> 4) << 2);
#pragma unroll
      for (int nf = 0; nf < 4; ++nf) {
        const int ci = (n0 + wn * 64 + nf * 16 + (lane & 15)) / 5;
#pragma unroll
        for (int mf = 0; mf < 4; ++mf)
#pragma unroll
          for (int r = 0; r < 4; ++r)
            if (rbase + mf * 16 + r == ci) ps += acc[mf][nf][r];
      }
    }
    for (int o = 32; o; o >>= 1) ps += __shfl_xor(ps, o);
    __shared__ float pls[4];
    if (lane == 0) pls[w] = ps;
    __syncthreads();
    if (tid == 0)
      posPart[blockIdx.y * 32 + blockIdx.x] = pls[0] + pls[1] + pls[2] + pls[3];
  }

  // Epilogue: p = exp2(dot*C - C); C/D layout: col=lane&15, row=(lane>>4)*4+reg
#pragma unroll
  for (int mf = 0; mf < 4; ++mf)
#pragma unroll
    for (int nf = 0; nf < 4; ++nf)
#pragma unroll
      for (int r = 0; r < 4; ++r)
        acc[mf][nf][r] = exp2f(acc[mf][nf][r] * C_EXP - C_EXP);

  // column sums over this wave's 64 rows
  float cs[4];
#pragma unroll
  for (int nf = 0; nf < 4; ++nf) {
    float s = 0.0f;
#pragma unroll
    for (int mf = 0; mf < 4; ++mf)
      s += acc[mf][nf][0] + acc[mf][nf][1] + acc[mf][nf][2] + acc[mf][nf][3];
    s += __shfl_xor(s, 16);
    s += __shfl_xor(s, 32);
    cs[nf] = s;
  }
  {
    int g = lane >> 4;                        // lane group g holds frag g's sums
    float v = (g == 0) ? cs[0] : (g == 1) ? cs[1] : (g == 2) ? cs[2] : cs[3];
    atomicAdd(&col_sum[n0 + wn * 64 + (g << 4) + (lane & 15)], v);
  }

  // row sums over this wave's 64 cols
#pragma unroll
  for (int mf = 0; mf < 4; ++mf) {
    floatx4 t = acc[mf][0] + acc[mf][1] + acc[mf][2] + acc[mf][3];
#pragma unroll
    for (int r = 0; r < 4; ++r) {
      float s = t[r];
      s += __shfl_xor(s, 1); s += __shfl_xor(s, 2);
      s += __shfl_xor(s, 4); s += __shfl_xor(s, 8);
      t[r] = s;
    }
    if ((lane & 15) < 4) {                    // 16 lanes cover 16 rows of this m-frag
      int q = lane & 3;
      float v = (q == 0) ? t[0] : (q == 1) ? t[1] : (q == 2) ? t[2] : t[3];
      atomicAdd(&row_sum[m0 + wm * 64 + mf * 16 + ((lane >> 4) << 2) + q], v);
    }
  }

  // --- last-block-done fused finish ---
  __syncthreads();                           // all this block's atomics issued+drained
  __shared__ unsigned int lastFlag;
  if (tid == 0) {
    __threadfence();                         // agent release (L2 writeback of posPart)
    lastFlag = (atomicAdd(cnt, 1u) == NBLK_ - 1) ? 1u : 0u;
  }
  __syncthreads();
  if (lastFlag) {
    __threadfence();                         // agent acquire (invalidate stale caches)
    float sA = 0.0f, sB = 0.0f, sP = 0.0f;
    for (int i = tid; i < B_;    i += 256) sA += logf(agent_load(&row_sum[i]));
    for (int i = tid; i < NN_;   i += 256) sB += logf(agent_load(&col_sum[i]));
    for (int i = tid; i < NBLK_; i += 256) sP += agent_load(&posPart[i]);
    float s = sA * (1.0f / B_) + sB * (1.0f / NN_)
            - sP * (2.0f * M_SHIFT / (float)NN_);
    for (int o = 32; o; o >>= 1) s += __shfl_xor(s, o);
    __shared__ float fls[4];
    if (lane == 0) fls[w] = s;
    __syncthreads();
    if (tid == 0)
      out[0] = M_SHIFT + 0.5f * (fls[0] + fls[1] + fls[2] + fls[3]);
  }
}

// ---------------------------------------------------------------------------
extern "C" void kernel_launch(void* const* d_in, const int* in_sizes, int n_in,
                              void* d_out, int out_size, void* d_ws, size_t ws_size,
                              hipStream_t stream) {
  const float* img = (const float*)d_in[0];   // (4096, 512) fp32
  const float* txt = (const float*)d_in[1];   // (4096, 5, 512) fp32

  // workspace: [ img_f16 | txt_f16 | row_sum(B) col_sum(NN) posPart(NBLK) cnt ]
  const size_t halfBytes = (size_t)(B_ * D_ + NN_ * D_) * 2;      // 25,165,824
  const size_t needBytes = halfBytes + (size_t)(B_ + NN_ + NBLK_ + 1) * 4;
  if (ws_size < needBytes) return;            // fail loudly (absmax), don't fault

  _Float16* Ah  = (_Float16*)d_ws;            // B*D halves (txt follows contiguously)
  _Float16* Bh  = Ah + B_ * D_;               // NN*D halves
  float* acc    = (float*)((char*)d_ws + halfBytes);
  float* row_s  = acc;                        // [0, B_)
  float* col_s  = acc + B_;                   // [B_, B_+NN_)
  float* posP   = acc + B_ + NN_;             // [B_+NN_, +NBLK_)
  unsigned int* cnt = (unsigned int*)(acc + B_ + NN_ + NBLK_);

  cvt_kernel <<<2048, 256, 0, stream>>>(img, txt, Ah, acc, cnt);
  gemm_kernel<<<dim3(32, 160), 256, 0, stream>>>(Ah, Bh, row_s, col_s, posP, cnt,
                                                 (float*)d_out);
}

// Round 11
// 167.084 us; speedup vs baseline: 2.0560x; 2.0560x over previous
//
#include <hip/hip_runtime.h>
#include <stdint.h>

// Shapes (fixed by the reference)
#define B_  4096
#define V_  5
#define D_  512
#define NN_ (B_ * V_)            // 20480 text rows
#define NBLK_ 5120               // gemm grid 32 x 160

// p = exp((dot - 1)/T) = exp2(dot*C - C), C = log2(e)/T
#define C_EXP 20.609929155556620f   // 1.4426950408889634 / 0.07
#define M_SHIFT (1.0f / 0.07f)

typedef float floatx4 __attribute__((ext_vector_type(4)));

// async global->LDS DMA, 16B per lane; LDS dest = wave-uniform base + lane*16
__device__ __forceinline__ void load_lds16(const void* g, void* l) {
  __builtin_amdgcn_global_load_lds(
      (const __attribute__((address_space(1))) unsigned int*)g,
      (__attribute__((address_space(3))) unsigned int*)l,
      16, 0, 0);
}

// ---------------------------------------------------------------------------
// Kernel 1: streaming fp32 -> fp8(e4m3) convert + accumulator zeroing.
// 3072 blocks x 256 threads x 16 floats = 12,582,912 exact (img first:
// 131072 groups, boundary exact). 16B stores (int4 of packed fp8).
// v_cvt_pk_fp8_f32 packs 2 fp32 -> 2 fp8 bytes; HW format matches the
// fp8 MFMA's interpretation (same chip), so encoding details cancel.
// ---------------------------------------------------------------------------
__global__ void cvt_kernel(const float* __restrict__ img, const float* __restrict__ txt,
                           uint8_t* __restrict__ out8, float* __restrict__ acc) {
  const int t = blockIdx.x * 256 + threadIdx.x;     // 16-float group index
  if (t < B_ + NN_) acc[t] = 0.0f;                  // zero row/col sums
  const float4* src; int g;
  if (t < (B_ * D_) / 16) { src = (const float4*)img; g = t; }
  else                    { src = (const float4*)txt; g = t - (B_ * D_) / 16; }
  float4 a = src[4 * g + 0], b = src[4 * g + 1];
  float4 c = src[4 * g + 2], d = src[4 * g + 3];
  int w0 = __builtin_amdgcn_cvt_pk_fp8_f32(a.x, a.y, 0, 0);
  w0     = __builtin_amdgcn_cvt_pk_fp8_f32(a.z, a.w, w0, 1);
  int w1 = __builtin_amdgcn_cvt_pk_fp8_f32(b.x, b.y, 0, 0);
  w1     = __builtin_amdgcn_cvt_pk_fp8_f32(b.z, b.w, w1, 1);
  int w2 = __builtin_amdgcn_cvt_pk_fp8_f32(c.x, c.y, 0, 0);
  w2     = __builtin_amdgcn_cvt_pk_fp8_f32(c.z, c.w, w2, 1);
  int w3 = __builtin_amdgcn_cvt_pk_fp8_f32(d.x, d.y, 0, 0);
  w3     = __builtin_amdgcn_cvt_pk_fp8_f32(d.z, d.w, w3, 1);
  ((int4*)out8)[t] = make_int4(w0, w1, w2, w3);
}

// ---------------------------------------------------------------------------
// Kernel 2: fused fp8 GEMM + exp + row/col sums + positives.
// 128x128 tile, K-tiles of 64 bytes (BK=64), 4 waves 2x2 (wave tile 64x64),
// mfma_f32_16x16x32_fp8_fp8 (f16 rate, HALF the LDS/DMA bytes of r9).
// LDS rows are 128x64B — identical geometry to r9's verified layout, same
// XOR 16B-chunk swizzle (LDS(r,c)=global chunk c^((r>>1)&3)); b64 frag
// reads land 2-way/bank-pair = free (m136). Superstep = 2 K-tiles = K128:
// 4 supersteps -> 4 vmcnt-bearing drains per block (r9 had 8).
// r10 lesson: NO device-scope fences in here.
// ---------------------------------------------------------------------------
__global__ __launch_bounds__(256, 3)
void gemm_kernel(const uint8_t* __restrict__ Ah, const uint8_t* __restrict__ Bh,
                 float* __restrict__ row_sum, float* __restrict__ col_sum,
                 float* __restrict__ posPart) {
  __shared__ __align__(16) uint8_t As[2][128 * 64];   // 8 KB each
  __shared__ __align__(16) uint8_t Bs[2][128 * 64];
  const int tid  = threadIdx.x;
  const int lane = tid & 63;
  const int w    = tid >> 6;                 // wave 0..3
  const int wm   = w >> 1, wn = w & 1;       // 2x2 wave grid
  const int m0   = blockIdx.x * 128;
  const int n0   = blockIdx.y * 128;

  floatx4 acc[4][4] = {};

  // --- staging (swizzled, same algebra as r9): lane L -> row L>>2, phys
  // chunk L&3; fetches global chunk (L&3)^((L>>3)&3).
  const int sc = ((lane & 3) ^ ((lane >> 3) & 3)) * 16;    // bytes
  const uint8_t* gA = Ah + (size_t)(m0 + w * 32 + (lane >> 2)) * D_ + sc;
  const uint8_t* gB = Bh + (size_t)(n0 + w * 32 + (lane >> 2)) * D_ + sc;
  const int lofs = (w * 32) * 64;            // wave-uniform LDS offset (bytes)

  // --- fragment addressing: lane needs bytes kk*32 + (lane>>4)*8 of row fr.
  // global chunk16 = kk*2 + (lane>>5); phys = global ^ ((fr>>1)&3)
  // (row = wm*64 + f*16 + fr: the f*16/wm*64 terms vanish mod the swizzle bits)
  const int fr  = lane & 15;
  const int swz = (fr >> 1) & 3;
  const int cg  = lane >> 5;                 // 0/1
  const int sub = ((lane >> 4) & 1) * 8;     // 0/8
  const int off0 = ((0 + cg) ^ swz) * 16 + sub;   // kk=0
  const int off1 = ((2 + cg) ^ swz) * 16 + sub;   // kk=1

  // prologue: K-tile 0 -> buf0, K-tile 1 -> buf1 (tile t at byte offset t*64)
  load_lds16(gA,                &As[0][lofs]);
  load_lds16(gA + 16 * D_,      &As[0][lofs + 16 * 64]);
  load_lds16(gB,                &Bs[0][lofs]);
  load_lds16(gB + 16 * D_,      &Bs[0][lofs + 16 * 64]);
  load_lds16(gA + 64,           &As[1][lofs]);
  load_lds16(gA + 64 + 16 * D_, &As[1][lofs + 16 * 64]);
  load_lds16(gB + 64,           &Bs[1][lofs]);
  load_lds16(gB + 64 + 16 * D_, &Bs[1][lofs + 16 * 64]);

  for (int ss = 0; ss < 4; ++ss) {           // 4 supersteps x 128 K = 512
    __syncthreads();   // barrier A: drains DMAs issued a full superstep ago

    long af[2][2][4], bf[2][2][4];           // [buf][kk][frag]
#pragma unroll
    for (int p = 0; p < 2; ++p)
#pragma unroll
      for (int f = 0; f < 4; ++f) {
        const uint8_t* Ar = &As[p][(wm * 64 + f * 16 + fr) * 64];
        const uint8_t* Br = &Bs[p][(wn * 64 + f * 16 + fr) * 64];
        af[p][0][f] = *(const long*)(Ar + off0);
        af[p][1][f] = *(const long*)(Ar + off1);
        bf[p][0][f] = *(const long*)(Br + off0);
        bf[p][1][f] = *(const long*)(Br + off1);
      }

    __syncthreads();   // barrier B: cheap (vmcnt already 0)

    if (ss < 3) {      // stage K-tiles 2ss+2, 2ss+3 (overlap the MFMAs below)
      const int kg = (2 * ss + 2) * 64;
      load_lds16(gA + kg,                &As[0][lofs]);
      load_lds16(gA + kg + 16 * D_,      &As[0][lofs + 16 * 64]);
      load_lds16(gB + kg,                &Bs[0][lofs]);
      load_lds16(gB + kg + 16 * D_,      &Bs[0][lofs + 16 * 64]);
      load_lds16(gA + kg + 64,           &As[1][lofs]);
      load_lds16(gA + kg + 64 + 16 * D_, &As[1][lofs + 16 * 64]);
      load_lds16(gB + kg + 64,           &Bs[1][lofs]);
      load_lds16(gB + kg + 64 + 16 * D_, &Bs[1][lofs + 16 * 64]);
    }

#pragma unroll
    for (int p = 0; p < 2; ++p)
#pragma unroll
      for (int kk = 0; kk < 2; ++kk)
#pragma unroll
        for (int mf = 0; mf < 4; ++mf)
#pragma unroll
          for (int nf = 0; nf < 4; ++nf)
            acc[mf][nf] = __builtin_amdgcn_mfma_f32_16x16x32_fp8_fp8(
                af[p][kk][mf], bf[p][kk][nf], acc[mf][nf], 0, 0, 0);
  }

  // --- positive extraction from RAW acc (pre-exp): row == col/5 ---
  {
    float ps = 0.0f;
    const int iLo = n0 / 5, iHi = (n0 + 127) / 5;
    if (iHi >= m0 && iLo < m0 + 128) {       // block-uniform skip (~4/5 skip)
      const int rbase = m0 + wm * 64 + ((lane >> 4) << 2);
#pragma unroll
      for (int nf = 0; nf < 4; ++nf) {
        const int ci = (n0 + wn * 64 + nf * 16 + (lane & 15)) / 5;
#pragma unroll
        for (int mf = 0; mf < 4; ++mf)
#pragma unroll
          for (int r = 0; r < 4; ++r)
            if (rbase + mf * 16 + r == ci) ps += acc[mf][nf][r];
      }
    }
    for (int o = 32; o; o >>= 1) ps += __shfl_xor(ps, o);
    __shared__ float pls[4];
    if (lane == 0) pls[w] = ps;
    __syncthreads();
    if (tid == 0)
      posPart[blockIdx.y * 32 + blockIdx.x] = pls[0] + pls[1] + pls[2] + pls[3];
  }

  // Epilogue: p = exp2(dot*C - C); C/D layout: col=lane&15, row=(lane>>4)*4+reg
#pragma unroll
  for (int mf = 0; mf < 4; ++mf)
#pragma unroll
    for (int nf = 0; nf < 4; ++nf)
#pragma unroll
      for (int r = 0; r < 4; ++r)
        acc[mf][nf][r] = exp2f(acc[mf][nf][r] * C_EXP - C_EXP);

  // column sums over this wave's 64 rows
  float cs[4];
#pragma unroll
  for (int nf = 0; nf < 4; ++nf) {
    float s = 0.0f;
#pragma unroll
    for (int mf = 0; mf < 4; ++mf)
      s += acc[mf][nf][0] + acc[mf][nf][1] + acc[mf][nf][2] + acc[mf][nf][3];
    s += __shfl_xor(s, 16);
    s += __shfl_xor(s, 32);
    cs[nf] = s;
  }
  {
    int g = lane >> 4;                        // lane group g holds frag g's sums
    float v = (g == 0) ? cs[0] : (g == 1) ? cs[1] : (g == 2) ? cs[2] : cs[3];
    atomicAdd(&col_sum[n0 + wn * 64 + (g << 4) + (lane & 15)], v);
  }

  // row sums over this wave's 64 cols
#pragma unroll
  for (int mf = 0; mf < 4; ++mf) {
    floatx4 t = acc[mf][0] + acc[mf][1] + acc[mf][2] + acc[mf][3];
#pragma unroll
    for (int r = 0; r < 4; ++r) {
      float s = t[r];
      s += __shfl_xor(s, 1); s += __shfl_xor(s, 2);
      s += __shfl_xor(s, 4); s += __shfl_xor(s, 8);
      t[r] = s;
    }
    if ((lane & 15) < 4) {                    // 16 lanes cover 16 rows of this m-frag
      int q = lane & 3;
      float v = (q == 0) ? t[0] : (q == 1) ? t[1] : (q == 2) ? t[2] : t[3];
      atomicAdd(&row_sum[m0 + wm * 64 + mf * 16 + ((lane >> 4) << 2) + q], v);
    }
  }
}

// ---------------------------------------------------------------------------
// Kernel 3: loss = M + 0.5*(mean log rowsum + mean log colsum - 2*pos/(BV))
// pos (in dot units) = sum(posPart); scaled by M_SHIFT here.
// ---------------------------------------------------------------------------
__global__ void finish_kernel(const float* __restrict__ acc, const float* __restrict__ posPart,
                              float* __restrict__ out) {
  int tid = threadIdx.x;                     // single block, 1024 threads
  float sA = 0.0f, sB = 0.0f, sP = 0.0f;
  for (int i = tid; i < B_;    i += 1024) sA += logf(acc[i]);
  for (int i = tid; i < NN_;   i += 1024) sB += logf(acc[B_ + i]);
  for (int i = tid; i < NBLK_; i += 1024) sP += posPart[i];
  float s = sA * (1.0f / B_) + sB * (1.0f / NN_)
          - sP * (2.0f * M_SHIFT / (float)NN_);
  for (int o = 32; o; o >>= 1) s += __shfl_xor(s, o);
  __shared__ float ls[16];
  int lane = tid & 63, w = tid >> 6;
  if (lane == 0) ls[w] = s;
  __syncthreads();
  if (tid == 0) {
    float tot = 0.0f;
#pragma unroll
    for (int i = 0; i < 16; ++i) tot += ls[i];
    out[0] = M_SHIFT + 0.5f * tot;
  }
}

// ---------------------------------------------------------------------------
extern "C" void kernel_launch(void* const* d_in, const int* in_sizes, int n_in,
                              void* d_out, int out_size, void* d_ws, size_t ws_size,
                              hipStream_t stream) {
  const float* img = (const float*)d_in[0];   // (4096, 512) fp32
  const float* txt = (const float*)d_in[1];   // (4096, 5, 512) fp32

  // workspace: [ img_fp8 | txt_fp8 | row_sum(B) col_sum(NN) posPart(NBLK) ]
  const size_t fp8Bytes = (size_t)(B_ * D_ + NN_ * D_);           // 12,582,912
  const size_t needBytes = fp8Bytes + (size_t)(B_ + NN_ + NBLK_) * 4;
  if (ws_size < needBytes) return;            // fail loudly (absmax), don't fault

  uint8_t* Ah  = (uint8_t*)d_ws;              // B*D bytes (txt follows contiguously)
  uint8_t* Bh  = Ah + (size_t)B_ * D_;        // NN*D bytes
  float* acc   = (float*)((char*)d_ws + fp8Bytes);
  float* row_s = acc;                         // [0, B_)
  float* col_s = acc + B_;                    // [B_, B_+NN_)
  float* posP  = acc + B_ + NN_;              // [B_+NN_, +NBLK_)

  cvt_kernel   <<<3072, 256, 0, stream>>>(img, txt, Ah, acc);
  gemm_kernel  <<<dim3(32, 160), 256, 0, stream>>>(Ah, Bh, row_s, col_s, posP);
  finish_kernel<<<1, 1024, 0, stream>>>(acc, posP, (float*)d_out);
}

// Round 12
// 159.394 us; speedup vs baseline: 2.1552x; 1.0482x over previous
//
#include <hip/hip_runtime.h>
#include <stdint.h>

// Shapes (fixed by the reference)
#define B_  4096
#define V_  5
#define D_  512
#define NN_ (B_ * V_)            // 20480 text rows
#define NBLK_ 5120               // gemm grid 32 x 160

// p = exp((dot - 1)/T) = exp2(dot*C - C), C = log2(e)/T
#define C_EXP 20.609929155556620f   // 1.4426950408889634 / 0.07
#define M_SHIFT (1.0f / 0.07f)
#define SCALE1 0x7f7f7f7f           // e8m0 = 127 -> 2^0 in all 4 scale bytes

typedef float floatx4 __attribute__((ext_vector_type(4)));
typedef int   intx4   __attribute__((ext_vector_type(4)));
typedef int   intx8   __attribute__((ext_vector_type(8)));

// async global->LDS DMA, 16B per lane; LDS dest = wave-uniform base + lane*16
__device__ __forceinline__ void load_lds16(const void* g, void* l) {
  __builtin_amdgcn_global_load_lds(
      (const __attribute__((address_space(1))) unsigned int*)g,
      (__attribute__((address_space(3))) unsigned int*)l,
      16, 0, 0);
}

// ---------------------------------------------------------------------------
// Kernel 1: streaming fp32 -> fp8(e4m3) convert + accumulator zeroing.
// 3072 blocks x 256 threads x 16 floats = 12,582,912 exact. (unchanged r11)
// ---------------------------------------------------------------------------
__global__ void cvt_kernel(const float* __restrict__ img, const float* __restrict__ txt,
                           uint8_t* __restrict__ out8, float* __restrict__ acc) {
  const int t = blockIdx.x * 256 + threadIdx.x;     // 16-float group index
  if (t < B_ + NN_) acc[t] = 0.0f;                  // zero row/col sums
  const float4* src; int g;
  if (t < (B_ * D_) / 16) { src = (const float4*)img; g = t; }
  else                    { src = (const float4*)txt; g = t - (B_ * D_) / 16; }
  float4 a = src[4 * g + 0], b = src[4 * g + 1];
  float4 c = src[4 * g + 2], d = src[4 * g + 3];
  int w0 = __builtin_amdgcn_cvt_pk_fp8_f32(a.x, a.y, 0, 0);
  w0     = __builtin_amdgcn_cvt_pk_fp8_f32(a.z, a.w, w0, 1);
  int w1 = __builtin_amdgcn_cvt_pk_fp8_f32(b.x, b.y, 0, 0);
  w1     = __builtin_amdgcn_cvt_pk_fp8_f32(b.z, b.w, w1, 1);
  int w2 = __builtin_amdgcn_cvt_pk_fp8_f32(c.x, c.y, 0, 0);
  w2     = __builtin_amdgcn_cvt_pk_fp8_f32(c.z, c.w, w2, 1);
  int w3 = __builtin_amdgcn_cvt_pk_fp8_f32(d.x, d.y, 0, 0);
  w3     = __builtin_amdgcn_cvt_pk_fp8_f32(d.z, d.w, w3, 1);
  ((int4*)out8)[t] = make_int4(w0, w1, w2, w3);
}

// ---------------------------------------------------------------------------
// Kernel 2: fused MX-fp8 GEMM + exp + row/col sums + positives.
// mfma_scale_f32_16x16x128_f8f6f4, unit scales (identical math to r11's
// non-scaled fp8 -> absmax 0.0), K=128/instr: 64 MFMAs/wave (r11: 256).
// Staging identical to r11 (BK=64 tiles, XOR 16B-chunk swizzle, superstep
// = 2 tiles = one K=128 step, 4 vmcnt drains/block). Frag reads are now
// 2 x b128 per operand (32 contiguous k-bytes; lane q=lane>>4 -> buffer
// q>>1, 32B-half q&1) — per-phase bank-quads (r*4+swz)%8 all distinct
// => kills r11's 1.049e7 b64 conflicts.
// ---------------------------------------------------------------------------
__global__ __launch_bounds__(256, 3)
void gemm_kernel(const uint8_t* __restrict__ Ah, const uint8_t* __restrict__ Bh,
                 float* __restrict__ row_sum, float* __restrict__ col_sum,
                 float* __restrict__ posPart) {
  __shared__ __align__(16) uint8_t As[2 * 128 * 64];   // 16 KB (2 K-tiles)
  __shared__ __align__(16) uint8_t Bs[2 * 128 * 64];   // 16 KB
  const int tid  = threadIdx.x;
  const int lane = tid & 63;
  const int w    = tid >> 6;                 // wave 0..3
  const int wm   = w >> 1, wn = w & 1;       // 2x2 wave grid
  const int m0   = blockIdx.x * 128;
  const int n0   = blockIdx.y * 128;

  floatx4 acc[4][4] = {};

  // --- staging (swizzled, r9-verified): lane L -> row L>>2, phys chunk L&3;
  // fetches global chunk (L&3)^((L>>3)&3), i.e. LDS(r,c)=global c^((r>>1)&3).
  const int sc = ((lane & 3) ^ ((lane >> 3) & 3)) * 16;    // bytes
  const uint8_t* gA = Ah + (size_t)(m0 + w * 32 + (lane >> 2)) * D_ + sc;
  const uint8_t* gB = Bh + (size_t)(n0 + w * 32 + (lane >> 2)) * D_ + sc;
  const int lofs = (w * 32) * 64;            // wave-uniform LDS offset (bytes)

  // --- fragment addressing ---
  const int fr  = lane & 15;                 // frag m/n index
  const int swz = (fr >> 1) & 3;
  const int qb  = (lane >> 5) & 1;           // K-tile (buffer) select
  const int qh  = (lane >> 4) & 1;           // 32B half within 64B row
  const int c0  = ((qh * 2 + 0) ^ swz) * 16; // phys chunk offsets (bytes)
  const int c1  = ((qh * 2 + 1) ^ swz) * 16;
  const int bufo = qb * 8192;                // second K-tile at +8KB

  // prologue: K-tile 0 -> buf0, K-tile 1 -> buf1 (tile t at byte offset t*64)
  load_lds16(gA,                &As[lofs]);
  load_lds16(gA + 16 * D_,      &As[lofs + 16 * 64]);
  load_lds16(gB,                &Bs[lofs]);
  load_lds16(gB + 16 * D_,      &Bs[lofs + 16 * 64]);
  load_lds16(gA + 64,           &As[8192 + lofs]);
  load_lds16(gA + 64 + 16 * D_, &As[8192 + lofs + 16 * 64]);
  load_lds16(gB + 64,           &Bs[8192 + lofs]);
  load_lds16(gB + 64 + 16 * D_, &Bs[8192 + lofs + 16 * 64]);

  for (int ss = 0; ss < 4; ++ss) {           // 4 supersteps x 128 K = 512
    __syncthreads();   // barrier A: drains DMAs issued a full superstep ago

    intx8 af[4], bf[4];
#pragma unroll
    for (int f = 0; f < 4; ++f) {
      const uint8_t* Ar = As + bufo + (wm * 64 + f * 16 + fr) * 64;
      const uint8_t* Br = Bs + bufo + (wn * 64 + f * 16 + fr) * 64;
      intx4 alo = *(const intx4*)(Ar + c0);
      intx4 ahi = *(const intx4*)(Ar + c1);
      intx4 blo = *(const intx4*)(Br + c0);
      intx4 bhi = *(const intx4*)(Br + c1);
      af[f] = __builtin_shufflevector(alo, ahi, 0, 1, 2, 3, 4, 5, 6, 7);
      bf[f] = __builtin_shufflevector(blo, bhi, 0, 1, 2, 3, 4, 5, 6, 7);
    }

    __syncthreads();   // barrier B: cheap (vmcnt already 0)

    if (ss < 3) {      // stage K-tiles 2ss+2, 2ss+3 (overlap the MFMAs below)
      const int kg = (2 * ss + 2) * 64;
      load_lds16(gA + kg,                &As[lofs]);
      load_lds16(gA + kg + 16 * D_,      &As[lofs + 16 * 64]);
      load_lds16(gB + kg,                &Bs[lofs]);
      load_lds16(gB + kg + 16 * D_,      &Bs[lofs + 16 * 64]);
      load_lds16(gA + kg + 64,           &As[8192 + lofs]);
      load_lds16(gA + kg + 64 + 16 * D_, &As[8192 + lofs + 16 * 64]);
      load_lds16(gB + kg + 64,           &Bs[8192 + lofs]);
      load_lds16(gB + kg + 64 + 16 * D_, &Bs[8192 + lofs + 16 * 64]);
    }

#pragma unroll
    for (int mf = 0; mf < 4; ++mf)
#pragma unroll
      for (int nf = 0; nf < 4; ++nf)
        acc[mf][nf] = __builtin_amdgcn_mfma_scale_f32_16x16x128_f8f6f4(
            af[mf], bf[nf], acc[mf][nf],
            0, 0,                 // cbsz=FP8(e4m3), blgp=FP8(e4m3)
            0, SCALE1,            // opsel_a, scale_a = 1.0
            0, SCALE1);           // opsel_b, scale_b = 1.0
  }

  // --- positive extraction from RAW acc (pre-exp): row == col/5 ---
  {
    float ps = 0.0f;
    const int iLo = n0 / 5, iHi = (n0 + 127) / 5;
    if (iHi >= m0 && iLo < m0 + 128) {       // block-uniform skip (~4/5 skip)
      const int rbase = m0 + wm * 64 + ((lane >> 4) << 2);
#pragma unroll
      for (int nf = 0; nf < 4; ++nf) {
        const int ci = (n0 + wn * 64 + nf * 16 + (lane & 15)) / 5;
#pragma unroll
        for (int mf = 0; mf < 4; ++mf)
#pragma unroll
          for (int r = 0; r < 4; ++r)
            if (rbase + mf * 16 + r == ci) ps += acc[mf][nf][r];
      }
    }
    for (int o = 32; o; o >>= 1) ps += __shfl_xor(ps, o);
    __shared__ float pls[4];
    if (lane == 0) pls[w] = ps;
    __syncthreads();
    if (tid == 0)
      posPart[blockIdx.y * 32 + blockIdx.x] = pls[0] + pls[1] + pls[2] + pls[3];
  }

  // Epilogue: p = exp2(dot*C - C); C/D layout: col=lane&15, row=(lane>>4)*4+reg
#pragma unroll
  for (int mf = 0; mf < 4; ++mf)
#pragma unroll
    for (int nf = 0; nf < 4; ++nf)
#pragma unroll
      for (int r = 0; r < 4; ++r)
        acc[mf][nf][r] = exp2f(acc[mf][nf][r] * C_EXP - C_EXP);

  // column sums over this wave's 64 rows
  float cs[4];
#pragma unroll
  for (int nf = 0; nf < 4; ++nf) {
    float s = 0.0f;
#pragma unroll
    for (int mf = 0; mf < 4; ++mf)
      s += acc[mf][nf][0] + acc[mf][nf][1] + acc[mf][nf][2] + acc[mf][nf][3];
    s += __shfl_xor(s, 16);
    s += __shfl_xor(s, 32);
    cs[nf] = s;
  }
  {
    int g = lane >> 4;                        // lane group g holds frag g's sums
    float v = (g == 0) ? cs[0] : (g == 1) ? cs[1] : (g == 2) ? cs[2] : cs[3];
    atomicAdd(&col_sum[n0 + wn * 64 + (g << 4) + (lane & 15)], v);
  }

  // row sums over this wave's 64 cols
#pragma unroll
  for (int mf = 0; mf < 4; ++mf) {
    floatx4 t = acc[mf][0] + acc[mf][1] + acc[mf][2] + acc[mf][3];
#pragma unroll
    for (int r = 0; r < 4; ++r) {
      float s = t[r];
      s += __shfl_xor(s, 1); s += __shfl_xor(s, 2);
      s += __shfl_xor(s, 4); s += __shfl_xor(s, 8);
      t[r] = s;
    }
    if ((lane & 15) < 4) {                    // 16 lanes cover 16 rows of this m-frag
      int q = lane & 3;
      float v = (q == 0) ? t[0] : (q == 1) ? t[1] : (q == 2) ? t[2] : t[3];
      atomicAdd(&row_sum[m0 + wm * 64 + mf * 16 + ((lane >> 4) << 2) + q], v);
    }
  }
}

// ---------------------------------------------------------------------------
// Kernel 3: loss = M + 0.5*(mean log rowsum + mean log colsum - 2*pos/(BV))
// ---------------------------------------------------------------------------
__global__ void finish_kernel(const float* __restrict__ acc, const float* __restrict__ posPart,
                              float* __restrict__ out) {
  int tid = threadIdx.x;                     // single block, 1024 threads
  float sA = 0.0f, sB = 0.0f, sP = 0.0f;
  for (int i = tid; i < B_;    i += 1024) sA += logf(acc[i]);
  for (int i = tid; i < NN_;   i += 1024) sB += logf(acc[B_ + i]);
  for (int i = tid; i < NBLK_; i += 1024) sP += posPart[i];
  float s = sA * (1.0f / B_) + sB * (1.0f / NN_)
          - sP * (2.0f * M_SHIFT / (float)NN_);
  for (int o = 32; o; o >>= 1) s += __shfl_xor(s, o);
  __shared__ float ls[16];
  int lane = tid & 63, w = tid >> 6;
  if (lane == 0) ls[w] = s;
  __syncthreads();
  if (tid == 0) {
    float tot = 0.0f;
#pragma unroll
    for (int i = 0; i < 16; ++i) tot += ls[i];
    out[0] = M_SHIFT + 0.5f * tot;
  }
}

// ---------------------------------------------------------------------------
extern "C" void kernel_launch(void* const* d_in, const int* in_sizes, int n_in,
                              void* d_out, int out_size, void* d_ws, size_t ws_size,
                              hipStream_t stream) {
  const float* img = (const float*)d_in[0];   // (4096, 512) fp32
  const float* txt = (const float*)d_in[1];   // (4096, 5, 512) fp32

  // workspace: [ img_fp8 | txt_fp8 | row_sum(B) col_sum(NN) posPart(NBLK) ]
  const size_t fp8Bytes = (size_t)(B_ * D_ + NN_ * D_);           // 12,582,912
  const size_t needBytes = fp8Bytes + (size_t)(B_ + NN_ + NBLK_) * 4;
  if (ws_size < needBytes) return;            // fail loudly (absmax), don't fault

  uint8_t* Ah  = (uint8_t*)d_ws;              // B*D bytes (txt follows contiguously)
  uint8_t* Bh  = Ah + (size_t)B_ * D_;        // NN*D bytes
  float* acc   = (float*)((char*)d_ws + fp8Bytes);
  float* row_s = acc;                         // [0, B_)
  float* col_s = acc + B_;                    // [B_, B_+NN_)
  float* posP  = acc + B_ + NN_;              // [B_+NN_, +NBLK_)

  cvt_kernel   <<<3072, 256, 0, stream>>>(img, txt, Ah, acc);
  gemm_kernel  <<<dim3(32, 160), 256, 0, stream>>>(Ah, Bh, row_s, col_s, posP);
  finish_kernel<<<1, 1024, 0, stream>>>(acc, posP, (float*)d_out);
}